// Round 3
// baseline (674.502 us; speedup 1.0000x reference)
//
#include <hip/hip_runtime.h>
#include <hip/hip_bf16.h>

typedef __bf16 bf16_t;
typedef bf16_t bf16x8 __attribute__((ext_vector_type(8)));
typedef float  f32x4  __attribute__((ext_vector_type(4)));

constexpr int kN = 50000;   // nodes
constexpr int kE = 800000;  // edges
constexpr int kD = 128;     // D == H
constexpr int EPAD = 136;   // LDS row stride (bf16): +8 pad

__device__ __forceinline__ f32x4 mfma16(bf16x8 a, bf16x8 b, f32x4 c) {
  return __builtin_amdgcn_mfma_f32_16x16x32_bf16(a, b, c, 0, 0, 0);
}
__device__ __forceinline__ float silu_f(float x) {
  return x * (1.0f / (1.0f + __expf(-x)));
}

// ---------------- prep: bf16 conversions + weight transposes ----------------
__global__ void prep_kernel(const float* __restrict__ h,
                            const float* __restrict__ eW1, const float* __restrict__ eW2,
                            const float* __restrict__ nW1, const float* __restrict__ nW2,
                            bf16_t* __restrict__ h_bf,
                            bf16_t* __restrict__ W1T, bf16_t* __restrict__ W2T,
                            bf16_t* __restrict__ nW1T, bf16_t* __restrict__ nW2T) {
  const int idx = blockIdx.x * blockDim.x + threadIdx.x;
  const int stride = gridDim.x * blockDim.x;
  for (int i = idx; i < kN * kD; i += stride) h_bf[i] = (bf16_t)h[i];
  // W1T[n][k] = eW1[k][n]   (eW1 is [256][128] row-major)
  for (int i = idx; i < 256 * 128; i += stride) {
    const int n = i >> 8, k = i & 255;
    W1T[i]  = (bf16_t)eW1[k * 128 + n];
    nW1T[i] = (bf16_t)nW1[k * 128 + n];
  }
  for (int i = idx; i < 128 * 128; i += stride) {
    const int n = i >> 7, k = i & 127;
    W2T[i]  = (bf16_t)eW2[k * 128 + n];
    nW2T[i] = (bf16_t)nW2[k * 128 + n];
  }
}

// ---------------- P/Q precompute: P = h@eW1_top + eb1, Q = h@eW1_bot ----------------
__global__ __launch_bounds__(256, 2) void pq_kernel(
    const bf16_t* __restrict__ h_bf, const bf16_t* __restrict__ W1T,
    const float* __restrict__ eb1,
    bf16_t* __restrict__ P, bf16_t* __restrict__ Q) {
  __shared__ bf16_t t1[64 * EPAD];
  const int tid  = threadIdx.x;
  const int wv   = tid >> 6;
  const int lane = tid & 63;
  const int l16  = lane & 15;
  const int quad = lane >> 4;
  const int n0 = wv * 32 + l16;
  const int n1 = n0 + 16;
  const float b1v[2] = {eb1[n0], eb1[n1]};
  const int tb = blockIdx.x * 64;

  f32x4 accp[4][2], accq[4][2];
#pragma unroll
  for (int ms = 0; ms < 4; ++ms)
#pragma unroll
    for (int j = 0; j < 2; ++j) {
      accp[ms][j] = (f32x4){0.f, 0.f, 0.f, 0.f};
      accq[ms][j] = (f32x4){0.f, 0.f, 0.f, 0.f};
    }

#pragma unroll
  for (int ks = 0; ks < 4; ++ks) {
    const bf16_t* wp = W1T + ks * 32 + quad * 8;
    const bf16x8 bt0 = *(const bf16x8*)(wp + (size_t)n0 * 256);
    const bf16x8 bt1 = *(const bf16x8*)(wp + (size_t)n1 * 256);
    const bf16x8 bb0 = *(const bf16x8*)(wp + (size_t)n0 * 256 + 128);
    const bf16x8 bb1 = *(const bf16x8*)(wp + (size_t)n1 * 256 + 128);
#pragma unroll
    for (int ms = 0; ms < 4; ++ms) {
      int node = tb + ms * 16 + l16;
      node = node < kN ? node : kN - 1;
      const bf16x8 a = *(const bf16x8*)(h_bf + (size_t)node * kD + ks * 32 + quad * 8);
      accp[ms][0] = mfma16(a, bt0, accp[ms][0]);
      accp[ms][1] = mfma16(a, bt1, accp[ms][1]);
      accq[ms][0] = mfma16(a, bb0, accq[ms][0]);
      accq[ms][1] = mfma16(a, bb1, accq[ms][1]);
    }
  }

  // P: C-layout -> LDS (with bias) -> coalesced bf16x8 stores
#pragma unroll
  for (int ms = 0; ms < 4; ++ms)
#pragma unroll
    for (int j = 0; j < 2; ++j) {
      const int n = wv * 32 + j * 16 + l16;
#pragma unroll
      for (int r = 0; r < 4; ++r)
        t1[(ms * 16 + quad * 4 + r) * EPAD + n] = (bf16_t)(accp[ms][j][r] + b1v[j]);
    }
  __syncthreads();
  {
    const int row = tid >> 2, cc = (tid & 3) * 32;
    const int node = tb + row;
    if (node < kN) {
#pragma unroll
      for (int u = 0; u < 4; ++u)
        *(bf16x8*)(P + (size_t)node * kD + cc + u * 8) = *(const bf16x8*)&t1[row * EPAD + cc + u * 8];
    }
  }
  __syncthreads();
  // Q (no bias)
#pragma unroll
  for (int ms = 0; ms < 4; ++ms)
#pragma unroll
    for (int j = 0; j < 2; ++j) {
      const int n = wv * 32 + j * 16 + l16;
#pragma unroll
      for (int r = 0; r < 4; ++r)
        t1[(ms * 16 + quad * 4 + r) * EPAD + n] = (bf16_t)accq[ms][j][r];
    }
  __syncthreads();
  {
    const int row = tid >> 2, cc = (tid & 3) * 32;
    const int node = tb + row;
    if (node < kN) {
#pragma unroll
      for (int u = 0; u < 4; ++u)
        *(bf16x8*)(Q + (size_t)node * kD + cc + u * 8) = *(const bf16x8*)&t1[row * EPAD + cc + u * 8];
    }
  }
}

// ---------------- CSR build ----------------
__global__ void hist_kernel(const int* __restrict__ ei, int* __restrict__ hist) {
  const int idx = blockIdx.x * blockDim.x + threadIdx.x;
  const int stride = gridDim.x * blockDim.x;
  for (int e = idx; e < kE; e += stride) atomicAdd(&hist[ei[e]], 1);
}

__global__ void scan_kernel(const int* __restrict__ hist, int* __restrict__ cursor) {
  __shared__ int partial[1024];
  const int tid = threadIdx.x;
  constexpr int CH = (kN + 1023) / 1024;  // 49
  const int base = tid * CH;
  int s = 0;
#pragma unroll
  for (int i = 0; i < CH; ++i) {
    const int j = base + i;
    if (j < kN) s += hist[j];
  }
  partial[tid] = s;
  __syncthreads();
  for (int off = 1; off < 1024; off <<= 1) {
    int v = 0;
    if (tid >= off) v = partial[tid - off];
    __syncthreads();
    if (tid >= off) partial[tid] += v;
    __syncthreads();
  }
  int run = (tid == 0) ? 0 : partial[tid - 1];
#pragma unroll
  for (int i = 0; i < CH; ++i) {
    const int j = base + i;
    if (j < kN) {
      cursor[j] = run;
      run += hist[j];
    }
  }
}

__global__ void bucket_kernel(const int* __restrict__ ei, int* __restrict__ cursor,
                              int2* __restrict__ slot) {
  const int idx = blockIdx.x * blockDim.x + threadIdx.x;
  const int stride = gridDim.x * blockDim.x;
  for (int e = idx; e < kE; e += stride) {
    const int r = ei[e];
    const int c = ei[kE + e];
    const int pos = atomicAdd(&cursor[r], 1);
    slot[pos] = make_int2(r, c);
  }
}

// ---------------- edge kernel: e = silu(silu(P[row]+Q[col]) @ eW2 + eb2), segment-add ----------------
// No LDS, no barriers. Each wave owns a 16-edge m-slice of the 64-edge tile.
__global__ __launch_bounds__(256, 4) void edge_kernel(
    const bf16_t* __restrict__ P, const bf16_t* __restrict__ Q,
    const int2* __restrict__ slot,
    const bf16_t* __restrict__ W2T, const float* __restrict__ eb2,
    float* __restrict__ agg) {
  const int tid  = threadIdx.x;
  const int wv   = tid >> 6;
  const int lane = tid & 63;
  const int l16  = lane & 15;
  const int quad = lane >> 4;
  const int tb   = blockIdx.x * 64;
  const int mb   = wv * 16;

  const int2 rc = slot[tb + mb + l16];

  float b2v[8];
#pragma unroll
  for (int j = 0; j < 8; ++j) b2v[j] = eb2[j * 16 + l16];

  // A-fragments: e1[m][k] = silu(P[row][k] + Q[col][k]), m=l16, k=ks*32+quad*8+t
  bf16x8 afrag[4];
#pragma unroll
  for (int ks = 0; ks < 4; ++ks) {
    const bf16x8 p = *(const bf16x8*)(P + (size_t)rc.x * kD + ks * 32 + quad * 8);
    const bf16x8 q = *(const bf16x8*)(Q + (size_t)rc.y * kD + ks * 32 + quad * 8);
    bf16x8 a;
#pragma unroll
    for (int t = 0; t < 8; ++t) a[t] = (bf16_t)silu_f((float)p[t] + (float)q[t]);
    afrag[ks] = a;
  }

  f32x4 acc[8];
#pragma unroll
  for (int j = 0; j < 8; ++j) acc[j] = (f32x4){0.f, 0.f, 0.f, 0.f};

#pragma unroll
  for (int ks = 0; ks < 4; ++ks)
#pragma unroll
    for (int j = 0; j < 8; ++j) {
      const bf16x8 b = *(const bf16x8*)(W2T + (size_t)(j * 16 + l16) * kD + ks * 32 + quad * 8);
      acc[j] = mfma16(afrag[ks], b, acc[j]);
    }

  // epilogue: rows for output m = mb + quad*4 + r (sorted, nondecreasing)
  const int4 s0 = *(const int4*)(slot + tb + mb + quad * 4);
  const int4 s1 = *(const int4*)(slot + tb + mb + quad * 4 + 2);
  const int rows[4] = {s0.x, s0.z, s1.x, s1.z};

#pragma unroll
  for (int j = 0; j < 8; ++j) {
    const int n = j * 16 + l16;
    float run = silu_f(acc[j][0] + b2v[j]);
    int cur = rows[0];
#pragma unroll
    for (int r = 1; r < 4; ++r) {
      const float v = silu_f(acc[j][r] + b2v[j]);
      if (rows[r] == cur) {
        run += v;
      } else {
        atomicAdd(agg + (size_t)cur * kD + n, run);
        cur = rows[r];
        run = v;
      }
    }
    atomicAdd(agg + (size_t)cur * kD + n, run);
  }
}

// ---------------- node kernel: [h | agg] MLP + residual ----------------
__global__ __launch_bounds__(256, 2) void node_kernel(
    const bf16_t* __restrict__ h_bf, const float* __restrict__ h,
    const float* __restrict__ agg,
    const bf16_t* __restrict__ nW1T, const bf16_t* __restrict__ nW2T,
    const float* __restrict__ nb1, const float* __restrict__ nb2,
    float* __restrict__ out) {
  __shared__ bf16_t t1[64 * EPAD];
  const int tid  = threadIdx.x;
  const int wv   = tid >> 6;
  const int lane = tid & 63;
  const int l16  = lane & 15;
  const int quad = lane >> 4;
  const int n0 = wv * 32 + l16;
  const int n1 = n0 + 16;
  const float b1v[2] = {nb1[n0], nb1[n1]};
  const float b2v[2] = {nb2[n0], nb2[n1]};

  const int tb = blockIdx.x * 64;

  f32x4 acc[4][2];
#pragma unroll
  for (int ms = 0; ms < 4; ++ms)
#pragma unroll
    for (int j = 0; j < 2; ++j) acc[ms][j] = (f32x4){0.f, 0.f, 0.f, 0.f};

#pragma unroll
  for (int ks = 0; ks < 8; ++ks) {
    const bf16_t* wp = nW1T + ks * 32 + quad * 8;
    const bf16x8 b0 = *(const bf16x8*)(wp + (size_t)n0 * 256);
    const bf16x8 bq = *(const bf16x8*)(wp + (size_t)n1 * 256);
#pragma unroll
    for (int ms = 0; ms < 4; ++ms) {
      int node = tb + ms * 16 + l16;
      node = node < kN ? node : kN - 1;
      bf16x8 a;
      if (ks < 4) {
        a = *(const bf16x8*)(h_bf + (size_t)node * kD + ks * 32 + quad * 8);
      } else {
        const float4* p = (const float4*)(agg + (size_t)node * kD + (ks - 4) * 32 + quad * 8);
        const float4 f0 = p[0], f1 = p[1];
        a = (bf16x8){(bf16_t)f0.x, (bf16_t)f0.y, (bf16_t)f0.z, (bf16_t)f0.w,
                     (bf16_t)f1.x, (bf16_t)f1.y, (bf16_t)f1.z, (bf16_t)f1.w};
      }
      acc[ms][0] = mfma16(a, b0, acc[ms][0]);
      acc[ms][1] = mfma16(a, bq, acc[ms][1]);
    }
  }

#pragma unroll
  for (int ms = 0; ms < 4; ++ms)
#pragma unroll
    for (int j = 0; j < 2; ++j) {
      const int n = wv * 32 + j * 16 + l16;
#pragma unroll
      for (int r = 0; r < 4; ++r) {
        const int m = ms * 16 + quad * 4 + r;
        t1[m * EPAD + n] = (bf16_t)silu_f(acc[ms][j][r] + b1v[j]);
      }
    }
  __syncthreads();

  f32x4 acc2[4][2];
#pragma unroll
  for (int ms = 0; ms < 4; ++ms)
#pragma unroll
    for (int j = 0; j < 2; ++j) acc2[ms][j] = (f32x4){0.f, 0.f, 0.f, 0.f};
#pragma unroll
  for (int ks = 0; ks < 4; ++ks) {
    const bf16_t* wp = nW2T + ks * 32 + quad * 8;
    const bf16x8 b0 = *(const bf16x8*)(wp + (size_t)n0 * 128);
    const bf16x8 bq = *(const bf16x8*)(wp + (size_t)n1 * 128);
#pragma unroll
    for (int ms = 0; ms < 4; ++ms) {
      const bf16x8 a = *(const bf16x8*)&t1[(ms * 16 + l16) * EPAD + ks * 32 + quad * 8];
      acc2[ms][0] = mfma16(a, b0, acc2[ms][0]);
      acc2[ms][1] = mfma16(a, bq, acc2[ms][1]);
    }
  }

#pragma unroll
  for (int ms = 0; ms < 4; ++ms)
#pragma unroll
    for (int j = 0; j < 2; ++j) {
      const int n = wv * 32 + j * 16 + l16;
#pragma unroll
      for (int r = 0; r < 4; ++r) {
        const int node = tb + ms * 16 + quad * 4 + r;
        if (node < kN) {
          const size_t o = (size_t)node * kD + n;
          out[o] = h[o] + acc2[ms][j][r] + b2v[j];
        }
      }
    }
}

// ---------------- launch ----------------
extern "C" void kernel_launch(void* const* d_in, const int* in_sizes, int n_in,
                              void* d_out, int out_size, void* d_ws, size_t ws_size,
                              hipStream_t stream) {
  const float* h   = (const float*)d_in[0];
  const int*   ei  = (const int*)d_in[1];
  const float* eW1 = (const float*)d_in[2];
  const float* eb1 = (const float*)d_in[3];
  const float* eW2 = (const float*)d_in[4];
  const float* eb2 = (const float*)d_in[5];
  const float* nW1 = (const float*)d_in[6];
  const float* nb1 = (const float*)d_in[7];
  const float* nW2 = (const float*)d_in[8];
  const float* nb2 = (const float*)d_in[9];
  float* out = (float*)d_out;

  char* ws = (char*)d_ws;
  size_t off = 0;
  auto alloc = [&](size_t bytes) {
    void* p = ws + off;
    off += (bytes + 255) & ~(size_t)255;
    return p;
  };
  bf16_t* h_bf = (bf16_t*)alloc((size_t)kN * kD * 2);   // 12.8 MB
  bf16_t* W1T  = (bf16_t*)alloc(256 * 128 * 2);
  bf16_t* W2T  = (bf16_t*)alloc(128 * 128 * 2);
  bf16_t* nW1T = (bf16_t*)alloc(256 * 128 * 2);
  bf16_t* nW2T = (bf16_t*)alloc(128 * 128 * 2);
  bf16_t* P    = (bf16_t*)alloc((size_t)kN * kD * 2);   // 12.8 MB
  bf16_t* Q    = (bf16_t*)alloc((size_t)kN * kD * 2);   // 12.8 MB
  float*  agg  = (float*)alloc((size_t)kN * kD * 4);    // 25.6 MB
  int*  hist   = (int*)alloc((size_t)kN * 4);
  int*  cursor = (int*)alloc((size_t)kN * 4);
  int2* slot   = (int2*)alloc((size_t)kE * 8);          // 6.4 MB

  hipMemsetAsync(agg, 0, (size_t)kN * kD * 4, stream);
  hipMemsetAsync(hist, 0, (size_t)kN * 4, stream);
  prep_kernel<<<2048, 256, 0, stream>>>(h, eW1, eW2, nW1, nW2,
                                        h_bf, W1T, W2T, nW1T, nW2T);
  pq_kernel<<<(kN + 63) / 64, 256, 0, stream>>>(h_bf, W1T, eb1, P, Q);
  hist_kernel<<<1024, 256, 0, stream>>>(ei, hist);
  scan_kernel<<<1, 1024, 0, stream>>>(hist, cursor);
  bucket_kernel<<<1024, 256, 0, stream>>>(ei, cursor, slot);
  edge_kernel<<<kE / 64, 256, 0, stream>>>(P, Q, slot, W2T, eb2, agg);
  node_kernel<<<(kN + 63) / 64, 256, 0, stream>>>(h_bf, h, agg, nW1T, nW2T, nb1, nb2, out);
}

// Round 4
// 654.004 us; speedup vs baseline: 1.0313x; 1.0313x over previous
//
#include <hip/hip_runtime.h>
#include <hip/hip_bf16.h>

typedef __bf16 bf16_t;
typedef bf16_t bf16x8 __attribute__((ext_vector_type(8)));
typedef bf16_t bf16x4 __attribute__((ext_vector_type(4)));
typedef float  f32x4  __attribute__((ext_vector_type(4)));

constexpr int kN = 50000;   // nodes
constexpr int kE = 800000;  // edges
constexpr int kD = 128;     // D == H
constexpr int EPAD = 136;   // t1 LDS row stride (bf16)
constexpr int ASTR = 132;   // aggbuf LDS row stride (fp32)
constexpr int PQ_BLOCKS = (kN + 63) / 64;  // 782

__device__ __forceinline__ f32x4 mfma16(bf16x8 a, bf16x8 b, f32x4 c) {
  return __builtin_amdgcn_mfma_f32_16x16x32_bf16(a, b, c, 0, 0, 0);
}
__device__ __forceinline__ float silu_f(float x) {
  return x / (1.0f + __expf(-x));
}

// ---------------- K1: bf16 conversions + weight transposes + edge histogram ----------------
__global__ void prep_hist_kernel(const float* __restrict__ h, const int* __restrict__ ei,
                                 const float* __restrict__ eW1, const float* __restrict__ eW2,
                                 const float* __restrict__ nW1, const float* __restrict__ nW2,
                                 bf16_t* __restrict__ h_bf,
                                 bf16_t* __restrict__ W1T, bf16_t* __restrict__ W2T,
                                 bf16_t* __restrict__ nW1T, bf16_t* __restrict__ nW2T,
                                 int* __restrict__ hist) {
  const int idx = blockIdx.x * blockDim.x + threadIdx.x;
  const int stride = gridDim.x * blockDim.x;
  for (int i = idx; i < kN * kD / 4; i += stride) {
    const float4 f = ((const float4*)h)[i];
    const bf16x4 o = {(bf16_t)f.x, (bf16_t)f.y, (bf16_t)f.z, (bf16_t)f.w};
    ((bf16x4*)h_bf)[i] = o;
  }
  for (int i = idx; i < 256 * 128; i += stride) {
    const int n = i >> 8, k = i & 255;  // W1T[n][k] = eW1[k][n]
    W1T[i]  = (bf16_t)eW1[k * 128 + n];
    nW1T[i] = (bf16_t)nW1[k * 128 + n];
  }
  for (int i = idx; i < 128 * 128; i += stride) {
    const int n = i >> 7, k = i & 127;
    W2T[i]  = (bf16_t)eW2[k * 128 + n];
    nW2T[i] = (bf16_t)nW2[k * 128 + n];
  }
  for (int e = idx; e < kE; e += stride) atomicAdd(&hist[ei[e]], 1);
}

// ---------------- K2: exclusive scan -> rowptr (persistent) + cursor (consumed by bucket) ----------------
__global__ void scan_kernel(const int* __restrict__ hist,
                            int* __restrict__ rowptr, int* __restrict__ cursor) {
  __shared__ int partial[1024];
  const int tid = threadIdx.x;
  constexpr int CH = (kN + 1023) / 1024;  // 49
  const int base = tid * CH;
  int s = 0;
#pragma unroll
  for (int i = 0; i < CH; ++i) {
    const int j = base + i;
    if (j < kN) s += hist[j];
  }
  partial[tid] = s;
  __syncthreads();
  for (int off = 1; off < 1024; off <<= 1) {
    int v = 0;
    if (tid >= off) v = partial[tid - off];
    __syncthreads();
    if (tid >= off) partial[tid] += v;
    __syncthreads();
  }
  int run = (tid == 0) ? 0 : partial[tid - 1];
#pragma unroll
  for (int i = 0; i < CH; ++i) {
    const int j = base + i;
    if (j < kN) {
      rowptr[j] = run;
      cursor[j] = run;
      run += hist[j];
    }
  }
  if (tid == 0) rowptr[kN] = kE;
}

// ---------------- K3: bucket (blocks >= PQ_BLOCKS) + P/Q precompute (blocks < PQ_BLOCKS) ----------------
// P = h@eW1_top + eb1, Q = h@eW1_bot. Bucket packs slot word = (lrow<<16)|col, lrow = row & 63
// (valid because the fused kernel's node blocks are 64-aligned).
__global__ __launch_bounds__(256, 2) void bucket_pq_kernel(
    const int* __restrict__ ei, int* __restrict__ cursor, int* __restrict__ slot_lc,
    const bf16_t* __restrict__ h_bf, const bf16_t* __restrict__ W1T,
    const float* __restrict__ eb1,
    bf16_t* __restrict__ P, bf16_t* __restrict__ Q) {
  __shared__ bf16_t t1[64 * EPAD];

  if (blockIdx.x >= PQ_BLOCKS) {
    const int idx = (blockIdx.x - PQ_BLOCKS) * blockDim.x + threadIdx.x;
    const int stride = 512 * blockDim.x;
    for (int e = idx; e < kE; e += stride) {
      const int r = ei[e];
      const int c = ei[kE + e];
      const int pos = atomicAdd(&cursor[r], 1);
      slot_lc[pos] = ((r & 63) << 16) | c;
    }
    return;
  }

  const int tid  = threadIdx.x;
  const int wv   = tid >> 6;
  const int lane = tid & 63;
  const int l16  = lane & 15;
  const int quad = lane >> 4;
  const int n0 = wv * 32 + l16;
  const int n1 = n0 + 16;
  const float b1v[2] = {eb1[n0], eb1[n1]};
  const int tb = blockIdx.x * 64;

  f32x4 accp[4][2], accq[4][2];
#pragma unroll
  for (int ms = 0; ms < 4; ++ms)
#pragma unroll
    for (int j = 0; j < 2; ++j) {
      accp[ms][j] = (f32x4){0.f, 0.f, 0.f, 0.f};
      accq[ms][j] = (f32x4){0.f, 0.f, 0.f, 0.f};
    }

#pragma unroll
  for (int ks = 0; ks < 4; ++ks) {
    const bf16_t* wp = W1T + ks * 32 + quad * 8;
    const bf16x8 bt0 = *(const bf16x8*)(wp + (size_t)n0 * 256);
    const bf16x8 bt1 = *(const bf16x8*)(wp + (size_t)n1 * 256);
    const bf16x8 bb0 = *(const bf16x8*)(wp + (size_t)n0 * 256 + 128);
    const bf16x8 bb1 = *(const bf16x8*)(wp + (size_t)n1 * 256 + 128);
#pragma unroll
    for (int ms = 0; ms < 4; ++ms) {
      int node = tb + ms * 16 + l16;
      node = node < kN ? node : kN - 1;
      const bf16x8 a = *(const bf16x8*)(h_bf + (size_t)node * kD + ks * 32 + quad * 8);
      accp[ms][0] = mfma16(a, bt0, accp[ms][0]);
      accp[ms][1] = mfma16(a, bt1, accp[ms][1]);
      accq[ms][0] = mfma16(a, bb0, accq[ms][0]);
      accq[ms][1] = mfma16(a, bb1, accq[ms][1]);
    }
  }

#pragma unroll
  for (int ms = 0; ms < 4; ++ms)
#pragma unroll
    for (int j = 0; j < 2; ++j) {
      const int n = wv * 32 + j * 16 + l16;
#pragma unroll
      for (int r = 0; r < 4; ++r)
        t1[(ms * 16 + quad * 4 + r) * EPAD + n] = (bf16_t)(accp[ms][j][r] + b1v[j]);
    }
  __syncthreads();
  {
    const int row = tid >> 2, cc = (tid & 3) * 32;
    const int node = tb + row;
    if (node < kN) {
#pragma unroll
      for (int u = 0; u < 4; ++u)
        *(bf16x8*)(P + (size_t)node * kD + cc + u * 8) = *(const bf16x8*)&t1[row * EPAD + cc + u * 8];
    }
  }
  __syncthreads();
#pragma unroll
  for (int ms = 0; ms < 4; ++ms)
#pragma unroll
    for (int j = 0; j < 2; ++j) {
      const int n = wv * 32 + j * 16 + l16;
#pragma unroll
      for (int r = 0; r < 4; ++r)
        t1[(ms * 16 + quad * 4 + r) * EPAD + n] = (bf16_t)accq[ms][j][r];
    }
  __syncthreads();
  {
    const int row = tid >> 2, cc = (tid & 3) * 32;
    const int node = tb + row;
    if (node < kN) {
#pragma unroll
      for (int u = 0; u < 4; ++u)
        *(bf16x8*)(Q + (size_t)node * kD + cc + u * 8) = *(const bf16x8*)&t1[row * EPAD + cc + u * 8];
    }
  }
}

// ---------------- K4: fused node-centric edge MLP + LDS aggregate + node MLP ----------------
// Block b owns nodes [b*64, b*64+64) and their full CSR slot range. No global atomics.
__global__ __launch_bounds__(256, 3) void fused_kernel(
    const bf16_t* __restrict__ P, const bf16_t* __restrict__ Q,
    const int* __restrict__ slot_lc, const int* __restrict__ rowptr,
    const bf16_t* __restrict__ W2T, const float* __restrict__ eb2,
    const bf16_t* __restrict__ h_bf, const float* __restrict__ h,
    const bf16_t* __restrict__ nW1T, const bf16_t* __restrict__ nW2T,
    const float* __restrict__ nb1, const float* __restrict__ nb2,
    float* __restrict__ out) {
  __shared__ float aggbuf[64 * ASTR];  // 33792 B; aliased by t1 (17408 B) in node phase

  const int tid  = threadIdx.x;
  const int wv   = tid >> 6;
  const int lane = tid & 63;
  const int l16  = lane & 15;
  const int quad = lane >> 4;
  const int g0   = blockIdx.x * 64;

  for (int i = tid; i < 64 * ASTR; i += 256) aggbuf[i] = 0.0f;

  const int eb0 = rowptr[g0];
  const int eb1 = rowptr[min(g0 + 64, kN)];
  __syncthreads();

  float b2v[8];
#pragma unroll
  for (int j = 0; j < 8; ++j) b2v[j] = eb2[j * 16 + l16];

  // ---- edge phase: 128-edge block tiles, 32 edges per wave (2 m-slices) ----
  const int ntiles = (eb1 - eb0 + 127) >> 7;
  for (int t = 0; t < ntiles; ++t) {
    const int base = eb0 + t * 128 + wv * 32;

    int lr[2];
    bf16x8 af[2][4];
#pragma unroll
    for (int ms = 0; ms < 2; ++ms) {
      const int s = base + ms * 16 + l16;
      const bool val = s < eb1;
      const int lc = val ? slot_lc[s] : 0;
      lr[ms] = val ? (lc >> 16) : -1;
      const int cn = val ? (lc & 0xFFFF) : 0;
      const int pr = val ? (g0 + (lc >> 16)) : g0;
#pragma unroll
      for (int ks = 0; ks < 4; ++ks) {
        const bf16x8 p = *(const bf16x8*)(P + (size_t)pr * kD + ks * 32 + quad * 8);
        const bf16x8 q = *(const bf16x8*)(Q + (size_t)cn * kD + ks * 32 + quad * 8);
        bf16x8 a;
#pragma unroll
        for (int u = 0; u < 8; ++u) a[u] = (bf16_t)silu_f((float)p[u] + (float)q[u]);
        af[ms][ks] = a;
      }
    }

    f32x4 acc[2][8];
#pragma unroll
    for (int ms = 0; ms < 2; ++ms)
#pragma unroll
      for (int j = 0; j < 8; ++j) acc[ms][j] = (f32x4){0.f, 0.f, 0.f, 0.f};

#pragma unroll
    for (int ks = 0; ks < 4; ++ks)
#pragma unroll
      for (int j = 0; j < 8; ++j) {
        const bf16x8 b = *(const bf16x8*)(W2T + (size_t)(j * 16 + l16) * kD + ks * 32 + quad * 8);
        acc[0][j] = mfma16(af[0][ks], b, acc[0][j]);
        acc[1][j] = mfma16(af[1][ks], b, acc[1][j]);
      }

#pragma unroll
    for (int ms = 0; ms < 2; ++ms) {
      int rows[4];
#pragma unroll
      for (int r = 0; r < 4; ++r) rows[r] = __shfl(lr[ms], quad * 4 + r, 64);
#pragma unroll
      for (int j = 0; j < 8; ++j) {
        const int cbase = j * 16 + l16;
        float run = silu_f(acc[ms][j][0] + b2v[j]);
        int cur = rows[0];
#pragma unroll
        for (int r = 1; r < 4; ++r) {
          const float v = silu_f(acc[ms][j][r] + b2v[j]);
          if (rows[r] == cur) {
            run += v;
          } else {
            if (cur >= 0) atomicAdd(&aggbuf[cur * ASTR + cbase], run);
            cur = rows[r];
            run = v;
          }
        }
        if (cur >= 0) atomicAdd(&aggbuf[cur * ASTR + cbase], run);
      }
    }
  }
  __syncthreads();

  // ---- node phase: out = h + silu([h | agg] @ nW1 + nb1) @ nW2 + nb2 ----
  const int n0 = wv * 32 + l16;
  const int n1 = n0 + 16;
  const float b1v[2] = {nb1[n0], nb1[n1]};
  const float b2n[2] = {nb2[n0], nb2[n1]};

  f32x4 acc[4][2];
#pragma unroll
  for (int ms = 0; ms < 4; ++ms)
#pragma unroll
    for (int j = 0; j < 2; ++j) acc[ms][j] = (f32x4){0.f, 0.f, 0.f, 0.f};

#pragma unroll
  for (int ks = 0; ks < 8; ++ks) {
    const bf16_t* wp = nW1T + ks * 32 + quad * 8;
    const bf16x8 b0 = *(const bf16x8*)(wp + (size_t)n0 * 256);
    const bf16x8 bq = *(const bf16x8*)(wp + (size_t)n1 * 256);
#pragma unroll
    for (int ms = 0; ms < 4; ++ms) {
      bf16x8 a;
      if (ks < 4) {
        int node = g0 + ms * 16 + l16;
        node = node < kN ? node : kN - 1;
        a = *(const bf16x8*)(h_bf + (size_t)node * kD + ks * 32 + quad * 8);
      } else {
        const int lrow = ms * 16 + l16;
        const float* ap = &aggbuf[lrow * ASTR + (ks - 4) * 32 + quad * 8];
        const float4 f0 = *(const float4*)ap;
        const float4 f1 = *(const float4*)(ap + 4);
        a = (bf16x8){(bf16_t)f0.x, (bf16_t)f0.y, (bf16_t)f0.z, (bf16_t)f0.w,
                     (bf16_t)f1.x, (bf16_t)f1.y, (bf16_t)f1.z, (bf16_t)f1.w};
      }
      acc[ms][0] = mfma16(a, b0, acc[ms][0]);
      acc[ms][1] = mfma16(a, bq, acc[ms][1]);
    }
  }
  __syncthreads();  // all aggbuf reads complete before t1 aliases it

  bf16_t* t1 = (bf16_t*)aggbuf;
#pragma unroll
  for (int ms = 0; ms < 4; ++ms)
#pragma unroll
    for (int j = 0; j < 2; ++j) {
      const int n = wv * 32 + j * 16 + l16;
#pragma unroll
      for (int r = 0; r < 4; ++r) {
        const int m = ms * 16 + quad * 4 + r;
        t1[m * EPAD + n] = (bf16_t)silu_f(acc[ms][j][r] + b1v[j]);
      }
    }
  __syncthreads();

  f32x4 acc2[4][2];
#pragma unroll
  for (int ms = 0; ms < 4; ++ms)
#pragma unroll
    for (int j = 0; j < 2; ++j) acc2[ms][j] = (f32x4){0.f, 0.f, 0.f, 0.f};
#pragma unroll
  for (int ks = 0; ks < 4; ++ks) {
    const bf16_t* wp = nW2T + ks * 32 + quad * 8;
    const bf16x8 b0 = *(const bf16x8*)(wp + (size_t)n0 * 128);
    const bf16x8 bq = *(const bf16x8*)(wp + (size_t)n1 * 128);
#pragma unroll
    for (int ms = 0; ms < 4; ++ms) {
      const bf16x8 a = *(const bf16x8*)&t1[(ms * 16 + l16) * EPAD + ks * 32 + quad * 8];
      acc2[ms][0] = mfma16(a, b0, acc2[ms][0]);
      acc2[ms][1] = mfma16(a, bq, acc2[ms][1]);
    }
  }

#pragma unroll
  for (int ms = 0; ms < 4; ++ms)
#pragma unroll
    for (int j = 0; j < 2; ++j) {
      const int n = wv * 32 + j * 16 + l16;
#pragma unroll
      for (int r = 0; r < 4; ++r) {
        const int node = g0 + ms * 16 + quad * 4 + r;
        if (node < kN) {
          const size_t o = (size_t)node * kD + n;
          out[o] = h[o] + acc2[ms][j][r] + b2n[j];
        }
      }
    }
}

// ---------------- launch ----------------
extern "C" void kernel_launch(void* const* d_in, const int* in_sizes, int n_in,
                              void* d_out, int out_size, void* d_ws, size_t ws_size,
                              hipStream_t stream) {
  const float* h   = (const float*)d_in[0];
  const int*   ei  = (const int*)d_in[1];
  const float* eW1 = (const float*)d_in[2];
  const float* eb1 = (const float*)d_in[3];
  const float* eW2 = (const float*)d_in[4];
  const float* eb2 = (const float*)d_in[5];
  const float* nW1 = (const float*)d_in[6];
  const float* nb1 = (const float*)d_in[7];
  const float* nW2 = (const float*)d_in[8];
  const float* nb2 = (const float*)d_in[9];
  float* out = (float*)d_out;

  char* ws = (char*)d_ws;
  size_t off = 0;
  auto alloc = [&](size_t bytes) {
    void* p = ws + off;
    off += (bytes + 255) & ~(size_t)255;
    return p;
  };
  bf16_t* h_bf    = (bf16_t*)alloc((size_t)kN * kD * 2);  // 12.8 MB
  bf16_t* W1T     = (bf16_t*)alloc(256 * 128 * 2);
  bf16_t* W2T     = (bf16_t*)alloc(128 * 128 * 2);
  bf16_t* nW1T    = (bf16_t*)alloc(256 * 128 * 2);
  bf16_t* nW2T    = (bf16_t*)alloc(128 * 128 * 2);
  bf16_t* P       = (bf16_t*)alloc((size_t)kN * kD * 2);  // 12.8 MB
  bf16_t* Q       = (bf16_t*)alloc((size_t)kN * kD * 2);  // 12.8 MB
  int*    hist    = (int*)alloc((size_t)kN * 4);
  int*    rowptr  = (int*)alloc((size_t)(kN + 1) * 4);
  int*    cursor  = (int*)alloc((size_t)kN * 4);
  int*    slot_lc = (int*)alloc((size_t)kE * 4);          // 3.2 MB

  hipMemsetAsync(hist, 0, (size_t)kN * 4, stream);
  prep_hist_kernel<<<2048, 256, 0, stream>>>(h, ei, eW1, eW2, nW1, nW2,
                                             h_bf, W1T, W2T, nW1T, nW2T, hist);
  scan_kernel<<<1, 1024, 0, stream>>>(hist, rowptr, cursor);
  bucket_pq_kernel<<<PQ_BLOCKS + 512, 256, 0, stream>>>(ei, cursor, slot_lc,
                                                        h_bf, W1T, eb1, P, Q);
  fused_kernel<<<PQ_BLOCKS, 256, 0, stream>>>(P, Q, slot_lc, rowptr, W2T, eb2,
                                              h_bf, h, nW1T, nW2T, nb1, nb2, out);
}